// Round 1
// baseline (805.785 us; speedup 1.0000x reference)
//
#include <hip/hip_runtime.h>
#include <hip/hip_bf16.h>

// EGA layer (GAT-like, global per-head softmax over edges) on MI355X.
// Pipeline: GEMM -> per-node scores -> online global softmax -> edge scatter.
// All f32 this round (correctness first).

#define N_NODES 50000
#define N_EDGES 800000
#define IN_DIM  256
#define OUT_DIM 64
#define HEADS   8
#define NCOL    (HEADS * OUT_DIM)   // 512
#define NBLK_RED 1024               // partial-reduction blocks for edge softmax

// ---------------------------------------------------------------------------
// GEMM: Wh[n][h*64+o] = sum_d x[n][d] * W[h][d][o] + b[h][o]
// Block tile 64(M) x 64(N=one head) x 16(K). 256 threads, 4x4 micro-tile.
// ---------------------------------------------------------------------------
__global__ __launch_bounds__(256) void gemm_kernel(
    const float* __restrict__ x, const float* __restrict__ W,
    const float* __restrict__ b, float* __restrict__ Wh)
{
    __shared__ __align__(16) float As[16][68];  // [k][row], pad 68 -> 16B-aligned rows, 2-way-free banks
    __shared__ __align__(16) float Bs[16][64];  // [k][col]

    const int h    = blockIdx.y;          // head == 64-col tile
    const int row0 = blockIdx.x * 64;
    const int tid  = threadIdx.x;
    const int ty   = tid >> 4, tx = tid & 15;

    // A-load mapping: float4 per thread, 64 rows x 16 k
    const int ar = tid >> 2;
    const int ak = (tid & 3) * 4;
    // B-load mapping: float4 per thread, 16 k x 64 cols
    const int bk = tid >> 4;
    const int bc = (tid & 15) * 4;

    const float* Wb = W + (size_t)h * IN_DIM * OUT_DIM;

    float acc[4][4] = {};

    for (int k0 = 0; k0 < IN_DIM; k0 += 16) {
        float4 av = make_float4(0.f, 0.f, 0.f, 0.f);
        const int arow = row0 + ar;
        if (arow < N_NODES)
            av = *(const float4*)(x + (size_t)arow * IN_DIM + k0 + ak);
        As[ak + 0][ar] = av.x;
        As[ak + 1][ar] = av.y;
        As[ak + 2][ar] = av.z;
        As[ak + 3][ar] = av.w;

        float4 bv = *(const float4*)(Wb + (size_t)(k0 + bk) * OUT_DIM + bc);
        *(float4*)(&Bs[bk][bc]) = bv;

        __syncthreads();
        #pragma unroll
        for (int kk = 0; kk < 16; ++kk) {
            float4 aq = *(const float4*)(&As[kk][ty * 4]);
            float4 bq = *(const float4*)(&Bs[kk][tx * 4]);
            acc[0][0] += aq.x * bq.x; acc[0][1] += aq.x * bq.y;
            acc[0][2] += aq.x * bq.z; acc[0][3] += aq.x * bq.w;
            acc[1][0] += aq.y * bq.x; acc[1][1] += aq.y * bq.y;
            acc[1][2] += aq.y * bq.z; acc[1][3] += aq.y * bq.w;
            acc[2][0] += aq.z * bq.x; acc[2][1] += aq.z * bq.y;
            acc[2][2] += aq.z * bq.z; acc[2][3] += aq.z * bq.w;
            acc[3][0] += aq.w * bq.x; acc[3][1] += aq.w * bq.y;
            acc[3][2] += aq.w * bq.z; acc[3][3] += aq.w * bq.w;
        }
        __syncthreads();
    }

    const float4 bias = *(const float4*)(b + h * OUT_DIM + tx * 4);
    #pragma unroll
    for (int i = 0; i < 4; ++i) {
        const int r = row0 + ty * 4 + i;
        if (r < N_NODES) {
            float4 o;
            o.x = acc[i][0] + bias.x;
            o.y = acc[i][1] + bias.y;
            o.z = acc[i][2] + bias.z;
            o.w = acc[i][3] + bias.w;
            *(float4*)(Wh + (size_t)r * NCOL + h * OUT_DIM + tx * 4) = o;
        }
    }
}

// ---------------------------------------------------------------------------
// Per-node attention scores: s_src[n][h] = Wh[n][h][:]·a[h][:64],
//                            s_dst[n][h] = Wh[n][h][:]·a[h][64:]
// One wave per node; lane = o.
// ---------------------------------------------------------------------------
__global__ __launch_bounds__(256) void score_kernel(
    const float* __restrict__ Wh, const float* __restrict__ a,
    float* __restrict__ s_src, float* __restrict__ s_dst)
{
    const int node = (int)((blockIdx.x * 256 + threadIdx.x) >> 6);
    const int lane = threadIdx.x & 63;
    if (node >= N_NODES) return;
    const float* wn = Wh + (size_t)node * NCOL;
    #pragma unroll
    for (int h = 0; h < HEADS; ++h) {
        const float v  = wn[h * 64 + lane];
        float ps = v * a[h * 128 + lane];
        float pd = v * a[h * 128 + 64 + lane];
        #pragma unroll
        for (int off = 32; off > 0; off >>= 1) {
            ps += __shfl_down(ps, off);
            pd += __shfl_down(pd, off);
        }
        if (lane == 0) {
            s_src[node * 8 + h] = ps;
            s_dst[node * 8 + h] = pd;
        }
    }
}

// ---------------------------------------------------------------------------
// Online (max, sumexp) over all edges per head. Writes per-block partials.
// ---------------------------------------------------------------------------
__global__ __launch_bounds__(256) void edge_reduce_kernel(
    const int* __restrict__ ei, const float* __restrict__ s_src,
    const float* __restrict__ s_dst, float* __restrict__ partial)
{
    float m[8], l[8];
    #pragma unroll
    for (int h = 0; h < 8; ++h) { m[h] = -1e30f; l[h] = 0.f; }

    for (int e = blockIdx.x * 256 + threadIdx.x; e < N_EDGES; e += gridDim.x * 256) {
        const int row = ei[e];
        const int col = ei[N_EDGES + e];
        const float4 s0 = *(const float4*)(s_src + row * 8);
        const float4 s1 = *(const float4*)(s_src + row * 8 + 4);
        const float4 d0 = *(const float4*)(s_dst + col * 8);
        const float4 d1 = *(const float4*)(s_dst + col * 8 + 4);
        const float ev[8] = { s0.x + d0.x, s0.y + d0.y, s0.z + d0.z, s0.w + d0.w,
                              s1.x + d1.x, s1.y + d1.y, s1.z + d1.z, s1.w + d1.w };
        #pragma unroll
        for (int h = 0; h < 8; ++h) {
            float t = ev[h];
            t = t > 0.f ? t : 0.01f * t;     // leaky_relu 0.01
            if (t > m[h]) { l[h] = l[h] * __expf(m[h] - t) + 1.f; m[h] = t; }
            else          { l[h] += __expf(t - m[h]); }
        }
    }

    __shared__ float red[16][256];           // [h]=max, [8+h]=sum
    const int tid = threadIdx.x;
    #pragma unroll
    for (int h = 0; h < 8; ++h) { red[h][tid] = m[h]; red[8 + h][tid] = l[h]; }
    __syncthreads();
    for (int s = 128; s > 0; s >>= 1) {
        if (tid < s) {
            #pragma unroll
            for (int h = 0; h < 8; ++h) {
                float mo = red[h][tid + s], lo = red[8 + h][tid + s];
                float mm = red[h][tid],     ll = red[8 + h][tid];
                if (mo > mm) { ll = ll * __expf(mm - mo) + lo; mm = mo; }
                else         { ll += lo * __expf(mo - mm); }
                red[h][tid] = mm; red[8 + h][tid] = ll;
            }
        }
        __syncthreads();
    }
    if (tid == 0) {
        #pragma unroll
        for (int h = 0; h < 8; ++h) {
            partial[blockIdx.x * 16 + h]     = red[h][0];
            partial[blockIdx.x * 16 + 8 + h] = red[8 + h][0];
        }
    }
}

// ---------------------------------------------------------------------------
// Merge partials -> coef[h] = global max M[h]; coef[8+h] = g[h]/L[h]
// (g = softmax(gate)).
// ---------------------------------------------------------------------------
__global__ void finalize_kernel(const float* __restrict__ partial,
                                const float* __restrict__ gate,
                                float* __restrict__ coef, int nblk)
{
    const int h = threadIdx.x;
    if (h >= 8) return;
    float m = -1e30f, l = 0.f;
    for (int bk = 0; bk < nblk; ++bk) {
        const float mb = partial[bk * 16 + h];
        const float lb = partial[bk * 16 + 8 + h];
        if (mb > m) { l = l * __expf(m - mb) + lb; m = mb; }
        else        { l += lb * __expf(mb - m); }
    }
    float gm = gate[0];
    for (int i = 1; i < 8; ++i) gm = fmaxf(gm, gate[i]);
    float gs = 0.f;
    for (int i = 0; i < 8; ++i) gs += __expf(gate[i] - gm);
    const float g = __expf(gate[h] - gm) / gs;
    coef[h]     = m;
    coef[8 + h] = g / l;
}

// ---------------------------------------------------------------------------
// Scatter: one wave per edge (lane = o).
// out[row][o] += sum_h w[h] * Wh[col][h][o],  w[h]=exp(e_h - M_h)*g_h/L_h
// ---------------------------------------------------------------------------
__global__ __launch_bounds__(256) void scatter_kernel(
    const int* __restrict__ ei, const float* __restrict__ s_src,
    const float* __restrict__ s_dst, const float* __restrict__ Wh,
    const float* __restrict__ coef, float* __restrict__ out)
{
    const int lane = threadIdx.x & 63;
    const int wid  = (int)((blockIdx.x * 256 + threadIdx.x) >> 6);
    const int nw   = (int)((gridDim.x * 256) >> 6);

    float M = 0.f, C = 0.f;
    if (lane < 8) { M = coef[lane]; C = coef[8 + lane]; }

    for (int e = wid; e < N_EDGES; e += nw) {
        const int row = ei[e];
        const int col = ei[N_EDGES + e];
        float w = 0.f;
        if (lane < 8) {
            float t = s_src[row * 8 + lane] + s_dst[col * 8 + lane];
            t = t > 0.f ? t : 0.01f * t;
            w = __expf(t - M) * C;
        }
        float acc = 0.f;
        const float* wc = Wh + (size_t)col * NCOL + lane;
        #pragma unroll
        for (int h = 0; h < 8; ++h)
            acc += __shfl(w, h) * wc[h * 64];
        atomicAdd(out + (size_t)row * OUT_DIM + lane, acc);
    }
}

// ---------------------------------------------------------------------------
extern "C" void kernel_launch(void* const* d_in, const int* in_sizes, int n_in,
                              void* d_out, int out_size, void* d_ws, size_t ws_size,
                              hipStream_t stream)
{
    const float* x    = (const float*)d_in[0];
    const int*   ei   = (const int*)  d_in[1];
    const float* W    = (const float*)d_in[2];
    const float* b    = (const float*)d_in[3];
    const float* a    = (const float*)d_in[4];
    const float* gate = (const float*)d_in[5];
    float* out = (float*)d_out;

    // workspace layout (floats): Wh | s_src | s_dst | partial | coef  (~106 MB)
    float* ws      = (float*)d_ws;
    float* Wh      = ws;
    float* s_src   = Wh    + (size_t)N_NODES * NCOL;
    float* s_dst   = s_src + (size_t)N_NODES * HEADS;
    float* partial = s_dst + (size_t)N_NODES * HEADS;
    float* coef    = partial + (size_t)NBLK_RED * 16;

    hipMemsetAsync(d_out, 0, (size_t)N_NODES * OUT_DIM * sizeof(float), stream);

    dim3 ggrid((N_NODES + 63) / 64, HEADS);
    gemm_kernel<<<ggrid, 256, 0, stream>>>(x, W, b, Wh);

    score_kernel<<<(N_NODES + 3) / 4, 256, 0, stream>>>(Wh, a, s_src, s_dst);

    edge_reduce_kernel<<<NBLK_RED, 256, 0, stream>>>(ei, s_src, s_dst, partial);

    finalize_kernel<<<1, 64, 0, stream>>>(partial, gate, coef, NBLK_RED);

    scatter_kernel<<<4096, 256, 0, stream>>>(ei, s_src, s_dst, Wh, coef, out);
}

// Round 2
// 345.344 us; speedup vs baseline: 2.3333x; 2.3333x over previous
//
#include <hip/hip_runtime.h>
#include <hip/hip_bf16.h>

// EGA layer (GAT-like, GLOBAL per-head softmax over edges) on MI355X.
// Pipeline: GEMM(+fused scores) -> online global softmax -> thresholded scatter.
// Global softmax over 800K edges with score std ~11 => weight mass concentrated
// in O(100) edges; scatter skips Wh gather + atomics for w < 1e-9 (error bound
// ~1e-6 per output element vs 7e-3 threshold). Deterministic, data-independent
// correctness (falls back to full work if scores are flat).

#define N_NODES 50000
#define N_EDGES 800000
#define IN_DIM  256
#define OUT_DIM 64
#define HEADS   8
#define NCOL    (HEADS * OUT_DIM)   // 512
#define NBLK_RED 1024               // partial-reduction blocks for edge softmax
#define LN_W_EPS (-20.72326584f)    // ln(1e-9) skip threshold

// ---------------------------------------------------------------------------
// GEMM: Wh[n][h*64+o] = sum_d x[n][d] * W[h][d][o] + b[h][o]
// Block tile 64(M) x 64(N=one head) x 16(K). 256 threads, 4x4 micro-tile.
// Epilogue also computes s_src[n][h] = Wh[n,h,:]·a[h,:64], s_dst likewise
// (cross-tx shfl reduction) -- saves a separate 102 MB pass.
// ---------------------------------------------------------------------------
__global__ __launch_bounds__(256) void gemm_kernel(
    const float* __restrict__ x, const float* __restrict__ W,
    const float* __restrict__ b, const float* __restrict__ a,
    float* __restrict__ Wh, float* __restrict__ s_src, float* __restrict__ s_dst)
{
    __shared__ __align__(16) float As[16][68];
    __shared__ __align__(16) float Bs[16][64];

    const int h    = blockIdx.y;          // head == 64-col tile
    const int row0 = blockIdx.x * 64;
    const int tid  = threadIdx.x;
    const int ty   = tid >> 4, tx = tid & 15;

    const int ar = tid >> 2;
    const int ak = (tid & 3) * 4;
    const int bk = tid >> 4;
    const int bc = (tid & 15) * 4;

    const float* Wb = W + (size_t)h * IN_DIM * OUT_DIM;

    float acc[4][4] = {};

    for (int k0 = 0; k0 < IN_DIM; k0 += 16) {
        float4 av = make_float4(0.f, 0.f, 0.f, 0.f);
        const int arow = row0 + ar;
        if (arow < N_NODES)
            av = *(const float4*)(x + (size_t)arow * IN_DIM + k0 + ak);
        As[ak + 0][ar] = av.x;
        As[ak + 1][ar] = av.y;
        As[ak + 2][ar] = av.z;
        As[ak + 3][ar] = av.w;

        float4 bv = *(const float4*)(Wb + (size_t)(k0 + bk) * OUT_DIM + bc);
        *(float4*)(&Bs[bk][bc]) = bv;

        __syncthreads();
        #pragma unroll
        for (int kk = 0; kk < 16; ++kk) {
            float4 aq = *(const float4*)(&As[kk][ty * 4]);
            float4 bq = *(const float4*)(&Bs[kk][tx * 4]);
            acc[0][0] += aq.x * bq.x; acc[0][1] += aq.x * bq.y;
            acc[0][2] += aq.x * bq.z; acc[0][3] += aq.x * bq.w;
            acc[1][0] += aq.y * bq.x; acc[1][1] += aq.y * bq.y;
            acc[1][2] += aq.y * bq.z; acc[1][3] += aq.y * bq.w;
            acc[2][0] += aq.z * bq.x; acc[2][1] += aq.z * bq.y;
            acc[2][2] += aq.z * bq.z; acc[2][3] += aq.z * bq.w;
            acc[3][0] += aq.w * bq.x; acc[3][1] += aq.w * bq.y;
            acc[3][2] += aq.w * bq.z; acc[3][3] += aq.w * bq.w;
        }
        __syncthreads();
    }

    const float4 bias  = *(const float4*)(b + h * OUT_DIM + tx * 4);
    const float4 asrc  = *(const float4*)(a + h * 128 + tx * 4);
    const float4 adst  = *(const float4*)(a + h * 128 + 64 + tx * 4);

    #pragma unroll
    for (int i = 0; i < 4; ++i) {
        const int r = row0 + ty * 4 + i;
        float4 o;
        o.x = acc[i][0] + bias.x;
        o.y = acc[i][1] + bias.y;
        o.z = acc[i][2] + bias.z;
        o.w = acc[i][3] + bias.w;
        if (r < N_NODES)
            *(float4*)(Wh + (size_t)r * NCOL + h * OUT_DIM + tx * 4) = o;

        float ps = o.x * asrc.x + o.y * asrc.y + o.z * asrc.z + o.w * asrc.w;
        float pd = o.x * adst.x + o.y * adst.y + o.z * adst.z + o.w * adst.w;
        #pragma unroll
        for (int m = 1; m < 16; m <<= 1) {
            ps += __shfl_xor(ps, m);
            pd += __shfl_xor(pd, m);
        }
        if (tx == 0 && r < N_NODES) {
            s_src[r * 8 + h] = ps;
            s_dst[r * 8 + h] = pd;
        }
    }
}

// ---------------------------------------------------------------------------
// Online (max, sumexp) over all edges per head. Writes per-block partials.
// ---------------------------------------------------------------------------
__global__ __launch_bounds__(256) void edge_reduce_kernel(
    const int* __restrict__ ei, const float* __restrict__ s_src,
    const float* __restrict__ s_dst, float* __restrict__ partial)
{
    float m[8], l[8];
    #pragma unroll
    for (int h = 0; h < 8; ++h) { m[h] = -1e30f; l[h] = 0.f; }

    for (int e = blockIdx.x * 256 + threadIdx.x; e < N_EDGES; e += gridDim.x * 256) {
        const int row = ei[e];
        const int col = ei[N_EDGES + e];
        const float4 s0 = *(const float4*)(s_src + row * 8);
        const float4 s1 = *(const float4*)(s_src + row * 8 + 4);
        const float4 d0 = *(const float4*)(s_dst + col * 8);
        const float4 d1 = *(const float4*)(s_dst + col * 8 + 4);
        const float ev[8] = { s0.x + d0.x, s0.y + d0.y, s0.z + d0.z, s0.w + d0.w,
                              s1.x + d1.x, s1.y + d1.y, s1.z + d1.z, s1.w + d1.w };
        #pragma unroll
        for (int h = 0; h < 8; ++h) {
            float t = ev[h];
            t = t > 0.f ? t : 0.01f * t;     // leaky_relu 0.01
            if (t > m[h]) { l[h] = l[h] * __expf(m[h] - t) + 1.f; m[h] = t; }
            else          { l[h] += __expf(t - m[h]); }
        }
    }

    __shared__ float red[16][256];
    const int tid = threadIdx.x;
    #pragma unroll
    for (int h = 0; h < 8; ++h) { red[h][tid] = m[h]; red[8 + h][tid] = l[h]; }
    __syncthreads();
    for (int s = 128; s > 0; s >>= 1) {
        if (tid < s) {
            #pragma unroll
            for (int h = 0; h < 8; ++h) {
                float mo = red[h][tid + s], lo = red[8 + h][tid + s];
                float mm = red[h][tid],     ll = red[8 + h][tid];
                if (mo > mm) { ll = ll * __expf(mm - mo) + lo; mm = mo; }
                else         { ll += lo * __expf(mo - mm); }
                red[h][tid] = mm; red[8 + h][tid] = ll;
            }
        }
        __syncthreads();
    }
    if (tid == 0) {
        #pragma unroll
        for (int h = 0; h < 8; ++h) {
            partial[blockIdx.x * 16 + h]     = red[h][0];
            partial[blockIdx.x * 16 + 8 + h] = red[8 + h][0];
        }
    }
}

// ---------------------------------------------------------------------------
// Merge partials. coef[h]=M_h, coef[8+h]=g_h/L_h, coef[16+h]=skip cutoff:
//   process edge iff exists h with t_h >= M_h + ln(eps) - ln(g_h/L_h).
// One wave; 8 threads per head merge strided chunks, shfl-combined.
// ---------------------------------------------------------------------------
__global__ void finalize_kernel(const float* __restrict__ partial,
                                const float* __restrict__ gate,
                                float* __restrict__ coef, int nblk)
{
    const int t = threadIdx.x;           // 64 threads: h = t&7, chunk j = t>>3
    const int h = t & 7;
    const int j = t >> 3;
    float m = -1e30f, l = 0.f;
    for (int bk = j; bk < nblk; bk += 8) {
        const float mb = partial[bk * 16 + h];
        const float lb = partial[bk * 16 + 8 + h];
        if (mb > m) { l = l * __expf(m - mb) + lb; m = mb; }
        else        { l += lb * __expf(mb - m); }
    }
    #pragma unroll
    for (int s = 8; s < 64; s <<= 1) {
        const float mo = __shfl_xor(m, s);
        const float lo = __shfl_xor(l, s);
        if (mo > m) { l = l * __expf(m - mo) + lo; m = mo; }
        else        { l += lo * __expf(mo - m); }
    }
    if (j == 0) {
        float gm = gate[0];
        for (int i = 1; i < 8; ++i) gm = fmaxf(gm, gate[i]);
        float gs = 0.f;
        for (int i = 0; i < 8; ++i) gs += __expf(gate[i] - gm);
        const float g = __expf(gate[h] - gm) / gs;
        const float C = g / l;
        coef[h]      = m;
        coef[8 + h]  = C;
        coef[16 + h] = m + LN_W_EPS - __logf(C);   // t >= cut  <=>  w >= eps
    }
}

// ---------------------------------------------------------------------------
// Thresholded scatter. One thread per edge for the cheap score test; the rare
// passing edges are processed wave-cooperatively (lane = output dim o).
// ---------------------------------------------------------------------------
__global__ __launch_bounds__(256) void scatter_kernel(
    const int* __restrict__ ei, const float* __restrict__ s_src,
    const float* __restrict__ s_dst, const float* __restrict__ Wh,
    const float* __restrict__ coef, float* __restrict__ out)
{
    __shared__ float cM[8], cC[8], cCut[8];
    if (threadIdx.x < 8)       cM[threadIdx.x]        = coef[threadIdx.x];
    else if (threadIdx.x < 16) cC[threadIdx.x - 8]    = coef[threadIdx.x];
    else if (threadIdx.x < 24) cCut[threadIdx.x - 16] = coef[threadIdx.x];
    __syncthreads();

    const int lane = threadIdx.x & 63;
    const int e    = blockIdx.x * 256 + threadIdx.x;   // grid == N_EDGES/256

    int row = 0, col = 0;
    bool pass = false;
    float w[8];
    if (e < N_EDGES) {
        row = ei[e];
        col = ei[N_EDGES + e];
        const float4 s0 = *(const float4*)(s_src + row * 8);
        const float4 s1 = *(const float4*)(s_src + row * 8 + 4);
        const float4 d0 = *(const float4*)(s_dst + col * 8);
        const float4 d1 = *(const float4*)(s_dst + col * 8 + 4);
        float t[8] = { s0.x + d0.x, s0.y + d0.y, s0.z + d0.z, s0.w + d0.w,
                       s1.x + d1.x, s1.y + d1.y, s1.z + d1.z, s1.w + d1.w };
        #pragma unroll
        for (int h = 0; h < 8; ++h) {
            t[h] = t[h] > 0.f ? t[h] : 0.01f * t[h];
            pass |= (t[h] >= cCut[h]);
        }
        if (pass) {
            #pragma unroll
            for (int h = 0; h < 8; ++h)
                w[h] = __expf(t[h] - cM[h]) * cC[h];
        }
    }

    unsigned long long mask = __ballot(pass);
    while (mask) {
        const int src = (int)__builtin_ctzll(mask);
        mask &= mask - 1;
        const int rb = __shfl(row, src);
        const int cb = __shfl(col, src);
        const float* wc = Wh + (size_t)cb * NCOL + lane;
        float acc = 0.f;
        #pragma unroll
        for (int h = 0; h < 8; ++h)
            acc += __shfl(w[h], src) * wc[h * 64];
        atomicAdd(out + (size_t)rb * OUT_DIM + lane, acc);
    }
}

// ---------------------------------------------------------------------------
extern "C" void kernel_launch(void* const* d_in, const int* in_sizes, int n_in,
                              void* d_out, int out_size, void* d_ws, size_t ws_size,
                              hipStream_t stream)
{
    const float* x    = (const float*)d_in[0];
    const int*   ei   = (const int*)  d_in[1];
    const float* W    = (const float*)d_in[2];
    const float* b    = (const float*)d_in[3];
    const float* a    = (const float*)d_in[4];
    const float* gate = (const float*)d_in[5];
    float* out = (float*)d_out;

    // workspace layout (floats): Wh | s_src | s_dst | partial | coef  (~106 MB)
    float* ws      = (float*)d_ws;
    float* Wh      = ws;
    float* s_src   = Wh    + (size_t)N_NODES * NCOL;
    float* s_dst   = s_src + (size_t)N_NODES * HEADS;
    float* partial = s_dst + (size_t)N_NODES * HEADS;
    float* coef    = partial + (size_t)NBLK_RED * 16;

    hipMemsetAsync(d_out, 0, (size_t)N_NODES * OUT_DIM * sizeof(float), stream);

    dim3 ggrid((N_NODES + 63) / 64, HEADS);
    gemm_kernel<<<ggrid, 256, 0, stream>>>(x, W, b, a, Wh, s_src, s_dst);

    edge_reduce_kernel<<<NBLK_RED, 256, 0, stream>>>(ei, s_src, s_dst, partial);

    finalize_kernel<<<1, 64, 0, stream>>>(partial, gate, coef, NBLK_RED);

    scatter_kernel<<<(N_EDGES + 255) / 256, 256, 0, stream>>>(
        ei, s_src, s_dst, Wh, coef, out);
}